// Round 3
// baseline (1057.861 us; speedup 1.0000x reference)
//
#include <hip/hip_runtime.h>

#define B_    4
#define N_    50000
#define E_    800000
#define FIN_  128
#define F_    64
#define BN_   (B_ * N_)        // 200000
#define TOT_  (BN_ * F_)       // 12,800,000
#define ALPHA_ 0.2f
#define NEG_BIG_ -9.0e15f

// X tile LDS row stride in floats: 132 -> row-to-row bank offset 4;
// within a wave only 4 distinct rows are read (16-lane broadcast each),
// banks k + {0,16,0,16} -> 2-way aliasing, free per m136.
#define XS_STRIDE 132

// ---- Kernel 1: h = X@W (fp32 -> d_out), e1 = h@a1, e2 = h@a2 (fp32 -> ws) --
// One block = 64 rows of the (BN x 128) X. BN % 64 == 0.
__global__ __launch_bounds__(256) void gemm_kernel(
    const float* __restrict__ X,
    const float* __restrict__ W,
    const float* __restrict__ a,
    float* __restrict__ h_out,
    float* __restrict__ e1,
    float* __restrict__ e2) {
    __shared__ float Wf[FIN_ * F_];            // 32 KB
    __shared__ float Xs[64 * XS_STRIDE];       // 33.8 KB

    const int tid = threadIdx.x;

    // Stage W: 8192 floats = 2048 float4, coalesced.
    const float4* Wg = (const float4*)W;
    for (int i = tid; i < 2048; i += 256)
        ((float4*)Wf)[i] = Wg[i];

    // Stage X tile: 64 rows x 32 float4.
    const int row0 = blockIdx.x * 64;
    const float4* Xg = (const float4*)(X + (size_t)row0 * FIN_);
    for (int i = tid; i < 2048; i += 256) {
        const int r = i >> 5;       // 32 float4 per 128-float row
        const int c = i & 31;
        float4 v = Xg[i];
        *(float4*)&Xs[r * XS_STRIDE + c * 4] = v;
    }
    __syncthreads();

    const int cg = tid & 15;   // cols 4*cg..4*cg+3
    const int rg = tid >> 4;   // rows 4*rg..4*rg+3

    float acc[4][4] = {};
#pragma unroll 4
    for (int k = 0; k < FIN_; ++k) {
        const float4 wv = *(const float4*)&Wf[k * F_ + cg * 4];
        float xr[4];
#pragma unroll
        for (int j = 0; j < 4; ++j)
            xr[j] = Xs[(rg * 4 + j) * XS_STRIDE + k];
#pragma unroll
        for (int j = 0; j < 4; ++j) {
            acc[j][0] += xr[j] * wv.x;
            acc[j][1] += xr[j] * wv.y;
            acc[j][2] += xr[j] * wv.z;
            acc[j][3] += xr[j] * wv.w;
        }
    }

    float a1v[4], a2v[4];
#pragma unroll
    for (int i = 0; i < 4; ++i) {
        a1v[i] = a[cg * 4 + i];
        a2v[i] = a[F_ + cg * 4 + i];
    }

#pragma unroll
    for (int j = 0; j < 4; ++j) {
        const int row = row0 + rg * 4 + j;
        float4 st = make_float4(acc[j][0], acc[j][1], acc[j][2], acc[j][3]);
        *(float4*)&h_out[(size_t)row * F_ + cg * 4] = st;

        float p1 = acc[j][0] * a1v[0] + acc[j][1] * a1v[1] +
                   acc[j][2] * a1v[2] + acc[j][3] * a1v[3];
        float p2 = acc[j][0] * a2v[0] + acc[j][1] * a2v[1] +
                   acc[j][2] * a2v[2] + acc[j][3] * a2v[3];
#pragma unroll
        for (int m = 8; m >= 1; m >>= 1) {   // reduce over cg (lane bits 0-3)
            p1 += __shfl_xor(p1, m);
            p2 += __shfl_xor(p2, m);
        }
        if (cg == 0) { e1[row] = p1; e2[row] = p2; }
    }
}

// ---- Kernel 2: per-edge scatter. One edge per wave, lane = feature. ------
// Handles nb batches starting at batch b0. hp/rowsum are LOCAL to this
// launch (size nb*N*64 / nb*N); edges/e1/e2/h are global-based.
__global__ __launch_bounds__(256) void edge_kernel(
    const int* __restrict__ edges,
    const float* __restrict__ e1,
    const float* __restrict__ e2,
    const float* __restrict__ h,
    float* __restrict__ hp,
    float* __restrict__ rowsum,
    int nb, int b0) {
    const int lane = threadIdx.x & 63;
    const int w0 = (int)((blockIdx.x * blockDim.x + threadIdx.x) >> 6);
    const int nw = (int)((gridDim.x * blockDim.x) >> 6);
    const int total = nb * E_;

    for (int g = w0; g < total; g += nw) {
        const int bl = g / E_;          // local batch
        const int e = g - bl * E_;
        const int b = b0 + bl;          // global batch
        const int s = edges[(size_t)b * 2 * E_ + e];
        const int d = edges[(size_t)b * 2 * E_ + E_ + e];
        const float sv = e1[b * N_ + s] + e2[b * N_ + d];
        const float lr = sv > 0.0f ? sv : ALPHA_ * sv;
        const float wt = __expf(-lr);
        const float hv = h[((size_t)b * N_ + d) * F_ + lane];
        atomicAdd(&hp[((size_t)bl * N_ + s) * F_ + lane], wt * hv);
        if (lane == 0) atomicAdd(&rowsum[bl * N_ + s], wt);
    }
}

// ---- Kernel 3: normalize + NaN->NEG_BIG + elu (fp32 out). ---------------
// Covers cnt = nb*N*64 contiguous elements; out pre-offset by caller.
__global__ __launch_bounds__(256) void out_kernel(
    const float* __restrict__ hp,
    const float* __restrict__ rowsum,
    float* __restrict__ out) {
    const int i = blockIdx.x * 256 + threadIdx.x;  // grid sized exactly
    float v = hp[i] / rowsum[i >> 6];
    if (v != v) v = NEG_BIG_;
    v = v > 0.0f ? v : (__expf(v) - 1.0f);
    out[i] = v;
}

extern "C" void kernel_launch(void* const* d_in, const int* in_sizes, int n_in,
                              void* d_out, int out_size, void* d_ws, size_t ws_size,
                              hipStream_t stream) {
    const float* X = (const float*)d_in[0];
    const int* edges = (const int*)d_in[1];
    const float* W = (const float*)d_in[2];
    const float* a = (const float*)d_in[3];
    float* h = (float*)d_out;   // h (fp32) lives in d_out, overwritten per batch

    // Full path needs: hp (B*N*64) + rowsum (B*N) + e1 (BN) + e2 (BN) floats.
    const size_t full_f = (size_t)B_ * N_ * F_ + 3 * (size_t)BN_;
    const bool full = ws_size >= full_f * sizeof(float);
    const int nb = full ? B_ : 1;

    float* hp = (float*)d_ws;
    float* rowsum = hp + (size_t)nb * N_ * F_;
    float* e1 = rowsum + (size_t)nb * N_;
    float* e2 = e1 + BN_;

    gemm_kernel<<<BN_ / 64, 256, 0, stream>>>(X, W, a, h, e1, e2);

    if (full) {
        hipMemsetAsync(hp, 0, ((size_t)B_ * N_ * F_ + (size_t)B_ * N_) * sizeof(float), stream);
        edge_kernel<<<8192, 256, 0, stream>>>(edges, e1, e2, h, hp, rowsum, B_, 0);
        out_kernel<<<TOT_ / 256, 256, 0, stream>>>(hp, rowsum, h);
    } else {
        for (int b = 0; b < B_; ++b) {
            hipMemsetAsync(hp, 0, ((size_t)N_ * F_ + N_) * sizeof(float), stream);
            edge_kernel<<<4096, 256, 0, stream>>>(edges, e1, e2, h, hp, rowsum, 1, b);
            out_kernel<<<(N_ * F_) / 256, 256, 0, stream>>>(
                hp, rowsum, h + (size_t)b * N_ * F_);
        }
    }
}